// Round 7
// baseline (332.286 us; speedup 1.0000x reference)
//
#include <hip/hip_runtime.h>
#include <cstdint>

typedef __attribute__((ext_vector_type(8))) short short8;
typedef __attribute__((ext_vector_type(4))) float f32x4;

#define NB 16
#define NT 2048
#define ND 1024
#define NC 512
#define NM (NB*NT)   // 32768 rows

#define BM 64        // rows per block
#define BKS 32       // K per stage
#define NSTAGE (ND/BKS)  // 32
#define NWAVE 8      // 512 threads

__device__ __forceinline__ unsigned short f2bf(float f){
  unsigned int u = __float_as_uint(f);
  u += 0x7fffu + ((u >> 16) & 1u);   // RNE; inputs are finite normals
  return (unsigned short)(u >> 16);
}

// ---------------- fused convert + pool + CAM GEMM + softmax ----------------
// Block: 512 threads (8 waves), one 64-row tile, full C=512 (softmax in-block).
//
// Single kernel replaces convert_pool + cam (removes the Ft 64MB write +
// 64MB read round-trip; F is read once, fp32, straight into the pipeline).
//
// A-path (reg-staged, T14 split): thread (row=tid>>3, kq=tid&7) loads one
// float4 of F per stage. Issue distance: fv for tile t+2 is loaded in the
// phase of tile t-? -> consumed 2 iterations (4 phases, >1200 cyc) later;
// cold-HBM latency fully covered. Convert to bf16 + ds_write_b64 at byte
// addr tid*8 (conflict-free) into frag-ordered As. All loads have register
// destinations -> the compiler's own fine-grained vmcnt ordering is exact;
// we only add raw s_barrier + lgkmcnt(0) publication (no vmcnt(0) drains).
//
// Pooling (fp32-exact, NO atomics — round-3's failure was same-address LDS
// atomics): per stage, butterfly __shfl_xor over the wave's 8 rows (strides
// 8/16/32), then lanes 0-7 accumulate float4 into pp[wave][k] (wave-private
// row -> race-free). After the K-loop: one cross-wave reduce -> part[r64].
//
// B-path unchanged from R5/R6: frag-ordered Wt, one coalesced 1-KB
// global_load_dwordx4 per (stage,ni) per wave, register double-buffered.
__global__ __launch_bounds__(512, 4) void cam_fused2_kernel(
    const float* __restrict__ F,             // fp32 [32768,1024]
    const unsigned short* __restrict__ Wt,   // bf16 frag-ordered [32][512][4][8e]
    float* __restrict__ part,                // [512][1024] pooling partials
    float* __restrict__ out_soft,
    float* __restrict__ out_raw)
{
  __shared__ alignas(16) unsigned short As[2][2048];   // 2 x 4 KB
  __shared__ alignas(16) float pp[NWAVE][ND];          // 32 KB pool partials
  __shared__ float redmax[NWAVE][BM];                  // 2 KB
  __shared__ float redsum[NWAVE][BM];                  // 2 KB

  const int tid    = threadIdx.x;
  const int wave   = tid >> 6;
  const int lane   = tid & 63;
  const int lane15 = lane & 15;
  const int quad   = lane >> 4;
  const int r64    = blockIdx.x;
  const int m0     = r64 * BM;
  const int chunk  = lane15 * 4 + quad;     // 0..63

  // A loader geometry
  const int arow = tid >> 3;     // 0..63
  const int akq  = tid & 7;      // float4 index within 32-k row

  // B per-lane base (elements): stage stride 16384, ni stride 512
  const unsigned short* wbase = Wt + wave * 2048 + chunk * 8;

  // zero pool accumulator (wave-private rows; in-order per wave, no barrier)
  #pragma unroll
  for (int e = 0; e < 16; e++) pp[wave][lane * 16 + e] = 0.f;

  f32x4 acc[4][4];
  #pragma unroll
  for (int mi = 0; mi < 4; mi++)
    #pragma unroll
    for (int ni = 0; ni < 4; ni++)
      acc[mi][ni] = (f32x4){0.f, 0.f, 0.f, 0.f};

  auto loadB = [&](short8* dst, int s) {
    const unsigned short* p = wbase + s * 16384;
    #pragma unroll
    for (int ni = 0; ni < 4; ni++)
      dst[ni] = *reinterpret_cast<const short8*>(p + ni * 512);
  };
  auto loadF = [&](int s) -> float4 {
    return *reinterpret_cast<const float4*>(
        F + (size_t)(m0 + arow) * ND + s * BKS + akq * 4);
  };
  auto writeA = [&](int buf, float4 v) {
    ushort4 s4;
    s4.x = f2bf(v.x); s4.y = f2bf(v.y); s4.z = f2bf(v.z); s4.w = f2bf(v.w);
    *reinterpret_cast<ushort4*>(&As[buf][tid * 4]) = s4;   // frag-order == tid*4
  };
  auto pool = [&](int s, float4 v) {
    float a0 = v.x, a1 = v.y, a2 = v.z, a3 = v.w;
    #pragma unroll
    for (int off = 8; off < 64; off <<= 1) {
      a0 += __shfl_xor(a0, off, 64);
      a1 += __shfl_xor(a1, off, 64);
      a2 += __shfl_xor(a2, off, 64);
      a3 += __shfl_xor(a3, off, 64);
    }
    if (lane < 8) {   // lane == kq; wave-private row of pp -> no race
      float4* p = reinterpret_cast<float4*>(&pp[wave][s * 32 + lane * 4]);
      float4 o = *p;
      o.x += a0; o.y += a1; o.z += a2; o.w += a3;
      *p = o;
    }
  };
  auto compute = [&](int buf, const short8* bf) {
    short8 af[4];
    #pragma unroll
    for (int mi = 0; mi < 4; mi++)
      af[mi] = *reinterpret_cast<const short8*>(&As[buf][mi * 512 + chunk * 8]);
    #pragma unroll
    for (int ni = 0; ni < 4; ni++)
      #pragma unroll
      for (int mi = 0; mi < 4; mi++)
        acc[mi][ni] = __builtin_amdgcn_mfma_f32_16x16x32_bf16(
            af[mi], bf[ni], acc[mi][ni], 0, 0, 0);
  };

  short8 b0[4], b1[4];
  float4 fvA, fvB;

  // ---- prologue: tiles 0,1 into As; B(0),B(1) in regs; fv = F(2),F(3) ----
  fvA = loadF(0); loadB(b0, 0);
  fvB = loadF(1); loadB(b1, 1);
  writeA(0, fvA); pool(0, fvA);
  writeA(1, fvB); pool(1, fvB);
  fvA = loadF(2);
  fvB = loadF(3);
  asm volatile("s_waitcnt lgkmcnt(0)" ::: "memory");
  __builtin_amdgcn_s_barrier();              // tiles 0,1 published

  #pragma unroll 1
  for (int t = 0; t < NSTAGE; t += 2) {
    // ---- even phase: tile t (As0, b0) ----
    __builtin_amdgcn_s_setprio(1);
    compute(0, b0);
    __builtin_amdgcn_s_setprio(0);
    if (t + 2 < NSTAGE) loadB(b0, t + 2);
    asm volatile("s_waitcnt lgkmcnt(0)" ::: "memory");
    __builtin_amdgcn_s_barrier();            // all waves done reading As0
    if (t + 2 < NSTAGE) { writeA(0, fvA); pool(t + 2, fvA); }   // fvA = F(t+2)
    if (t + 4 < NSTAGE) fvA = loadF(t + 4);  // 4-phase issue distance
    asm volatile("s_waitcnt lgkmcnt(0)" ::: "memory");
    __builtin_amdgcn_s_barrier();            // As0 = tile t+2 published

    // ---- odd phase: tile t+1 (As1, b1) ----
    __builtin_amdgcn_s_setprio(1);
    compute(1, b1);
    __builtin_amdgcn_s_setprio(0);
    if (t + 3 < NSTAGE) loadB(b1, t + 3);
    asm volatile("s_waitcnt lgkmcnt(0)" ::: "memory");
    __builtin_amdgcn_s_barrier();            // all waves done reading As1
    if (t + 3 < NSTAGE) { writeA(1, fvB); pool(t + 3, fvB); }   // fvB = F(t+3)
    if (t + 5 < NSTAGE) fvB = loadF(t + 5);
    asm volatile("s_waitcnt lgkmcnt(0)" ::: "memory");
    __builtin_amdgcn_s_barrier();            // As1 = tile t+3 published
  }

  // ---- flush pooling partials: part[r64][k] = sum over 8 waves ----
  #pragma unroll
  for (int i = 0; i < 2; i++) {
    const int k = tid + i * 512;
    float s = 0.f;
    #pragma unroll
    for (int w = 0; w < NWAVE; w++) s += pp[w][k];
    part[(size_t)r64 * ND + k] = s;
  }

  // ---- epilogue: fused softmax over C=512 ----
  // C/D layout: col = lane15 (+wave*64+ni*16), row = quad*4 + reg (+mi*16)
  #pragma unroll
  for (int mi = 0; mi < 4; mi++)
    #pragma unroll
    for (int r = 0; r < 4; r++) {
      float m = acc[mi][0][r];
      #pragma unroll
      for (int ni = 1; ni < 4; ni++) m = fmaxf(m, acc[mi][ni][r]);
      #pragma unroll
      for (int off = 1; off < 16; off <<= 1) m = fmaxf(m, __shfl_xor(m, off, 64));
      if (lane15 == 0) redmax[wave][mi * 16 + quad * 4 + r] = m;
    }
  __syncthreads();

  float rsum[4][4];
  #pragma unroll
  for (int mi = 0; mi < 4; mi++)
    #pragma unroll
    for (int r = 0; r < 4; r++) {
      const int row = mi * 16 + quad * 4 + r;
      float m = redmax[0][row];
      #pragma unroll
      for (int w = 1; w < NWAVE; w++) m = fmaxf(m, redmax[w][row]);
      float s = 0.f;
      #pragma unroll
      for (int ni = 0; ni < 4; ni++) {
        const float e = __expf(acc[mi][ni][r] - m);
        acc[mi][ni][r] = e;
        s += e;
      }
      #pragma unroll
      for (int off = 1; off < 16; off <<= 1) s += __shfl_xor(s, off, 64);
      rsum[mi][r] = s;
    }
  if (lane15 == 0) {
    #pragma unroll
    for (int mi = 0; mi < 4; mi++)
      #pragma unroll
      for (int r = 0; r < 4; r++)
        redsum[wave][mi * 16 + quad * 4 + r] = rsum[mi][r];
  }
  __syncthreads();

  #pragma unroll
  for (int mi = 0; mi < 4; mi++)
    #pragma unroll
    for (int r = 0; r < 4; r++) {
      const int row = mi * 16 + quad * 4 + r;
      float s = redsum[0][row];
      #pragma unroll
      for (int w = 1; w < NWAVE; w++) s += redsum[w][row];
      const float inv = 1.f / s;
      const size_t gr = (size_t)(m0 + row) * NC;
      #pragma unroll
      for (int ni = 0; ni < 4; ni++) {
        const int col = wave * 64 + ni * 16 + lane15;
        const float v = acc[mi][ni][r] * inv;
        out_soft[gr + col] = v;
        out_raw [gr + col] = v;
      }
    }
}

// ---------------- W fp32 -> Wt bf16 fragment-ordered ----------------
// chunk g: q = g&3, c = (g>>2)&511, s = g>>11; Wt[g*8..+8] = bf16(W[c][s*32+q*8..+8])
__global__ __launch_bounds__(256) void convw_kernel(
    const float* __restrict__ W, unsigned short* __restrict__ Wt)
{
  const int g = blockIdx.x * 256 + threadIdx.x;   // 0..65535
  const int q = g & 3, c = (g >> 2) & 511, s = g >> 11;
  const float* src = W + (size_t)c * ND + s * 32 + q * 8;
  const float4 a = *reinterpret_cast<const float4*>(src);
  const float4 b = *reinterpret_cast<const float4*>(src + 4);
  ushort4 lo, hi;
  lo.x = f2bf(a.x); lo.y = f2bf(a.y); lo.z = f2bf(a.z); lo.w = f2bf(a.w);
  hi.x = f2bf(b.x); hi.y = f2bf(b.y); hi.z = f2bf(b.z); hi.w = f2bf(b.w);
  *reinterpret_cast<ushort4*>(Wt + (size_t)g * 8)     = lo;
  *reinterpret_cast<ushort4*>(Wt + (size_t)g * 8 + 4) = hi;
}

// ---------------- logits = pooled @ W^T + b (fp32, parallel) ----------------
// grid (8 c-groups, 16 b), 512 threads = 64 c-lanes x 8 k-groups.
__global__ __launch_bounds__(512) void logits_kernel(
    const float* __restrict__ part, const float* __restrict__ W,
    const float* __restrict__ bias, float* __restrict__ out_logits)
{
  __shared__ float p[ND];          // pooled vector for this b (4 KB)
  __shared__ float red[8][64];     // k-group partials (2 KB)
  const int b   = blockIdx.y;
  const int cg  = blockIdx.x;
  const int tid = threadIdx.x;

  for (int i = tid; i < ND; i += 512) {
    float s = 0.f;
    #pragma unroll
    for (int z = 0; z < 32; z++) s += part[(size_t)(b * 32 + z) * ND + i];
    p[i] = s * (1.f / NT);
  }
  __syncthreads();

  const int cl = tid & 63;         // c within group
  const int kg = tid >> 6;         // k-group 0..7 (128 k each)
  const int c  = cg * 64 + cl;
  const float* wr = W + (size_t)c * ND + kg * 128;
  const float* pk = p + kg * 128;
  float s = 0.f;
  #pragma unroll
  for (int k4 = 0; k4 < 32; k4++) {
    const float4 wv = *reinterpret_cast<const float4*>(wr + k4 * 4);
    s = fmaf(pk[k4 * 4 + 0], wv.x, s);
    s = fmaf(pk[k4 * 4 + 1], wv.y, s);
    s = fmaf(pk[k4 * 4 + 2], wv.z, s);
    s = fmaf(pk[k4 * 4 + 3], wv.w, s);
  }
  red[kg][cl] = s;
  __syncthreads();
  if (tid < 64) {
    float t = 0.f;
    #pragma unroll
    for (int g = 0; g < 8; g++) t += red[g][tid];
    out_logits[b * NC + cg * 64 + tid] = t + bias[cg * 64 + tid];
  }
}

// ---------------- cross-entropy loss (fp32, wave-parallel) ----------------
__global__ __launch_bounds__(512) void loss_kernel(
    const float* __restrict__ logits, const int* __restrict__ labels,
    float* __restrict__ out_loss)
{
  __shared__ float term[16];
  const int tid  = threadIdx.x;
  const int wave = tid >> 6;
  const int lane = tid & 63;
  #pragma unroll
  for (int k = 0; k < 2; k++) {
    const int b = wave + k * 8;
    float v[8];
    float m = -3.4e38f;
    #pragma unroll
    for (int j = 0; j < 8; j++) {
      v[j] = logits[b * NC + j * 64 + lane];
      m = fmaxf(m, v[j]);
    }
    #pragma unroll
    for (int off = 1; off < 64; off <<= 1) m = fmaxf(m, __shfl_xor(m, off, 64));
    float e = 0.f;
    #pragma unroll
    for (int j = 0; j < 8; j++) e += expf(v[j] - m);
    #pragma unroll
    for (int off = 1; off < 64; off <<= 1) e += __shfl_xor(e, off, 64);
    if (lane == 0) {
      const int lab = labels[b];
      term[b] = -(logits[b * NC + lab] - m - logf(e));
    }
  }
  __syncthreads();
  if (tid == 0) {
    float a = 0.f;
    #pragma unroll
    for (int b = 0; b < 16; b++) a += term[b];
    out_loss[0] = a * (1.f / NB);
  }
}

extern "C" void kernel_launch(void* const* d_in, const int* in_sizes, int n_in,
                              void* d_out, int out_size, void* d_ws, size_t ws_size,
                              hipStream_t stream) {
  const float* F      = (const float*)d_in[0];   // [16,2048,1024]
  const int*   labels = (const int*)  d_in[1];   // [16]
  const float* W      = (const float*)d_in[2];   // [512,1024]
  const float* bias   = (const float*)d_in[3];   // [512]

  float* out        = (float*)d_out;
  float* out_soft   = out;
  float* out_raw    = out + (size_t)NM * NC;
  float* out_logits = out + (size_t)2 * NM * NC;
  float* out_loss   = out_logits + (size_t)NB * NC;

  // ws layout: part [0, 2 MiB) | Wt [2 MiB, 3 MiB)
  char* ws = (char*)d_ws;
  float* part = (float*)ws;                                     // 512*1024 f32
  unsigned short* Wt = (unsigned short*)(ws + (2u << 20));      // 32*512*4*8 bf16

  convw_kernel<<<NC * ND / (256 * 8), 256, 0, stream>>>(W, Wt);
  cam_fused2_kernel<<<NM / BM, 512, 0, stream>>>(F, Wt, part, out_soft, out_raw);
  logits_kernel<<<dim3(8, NB), 512, 0, stream>>>(part, W, bias, out_logits);
  loss_kernel<<<1, 512, 0, stream>>>(out_logits, labels, out_loss);
}

// Round 8
// 284.612 us; speedup vs baseline: 1.1675x; 1.1675x over previous
//
#include <hip/hip_runtime.h>
#include <cstdint>

typedef __attribute__((ext_vector_type(8))) short short8;
typedef __attribute__((ext_vector_type(4))) float f32x4;

#define NB 16
#define NT 2048
#define ND 1024
#define NC 512
#define NM (NB*NT)   // 32768 rows

#define BM 64        // rows per block
#define BKS 32       // K per stage
#define NSTAGE (ND/BKS)  // 32
#define NWAVE 8      // 512 threads

__device__ __forceinline__ unsigned short f2bf(float f){
  unsigned int u = __float_as_uint(f);
  u += 0x7fffu + ((u >> 16) & 1u);   // RNE; inputs are finite normals
  return (unsigned short)(u >> 16);
}

// async 16B global -> LDS DMA (per-lane global src; wave-uniform LDS base + lane*16)
__device__ __forceinline__ void async_copy16(const void* g, void* l) {
  __builtin_amdgcn_global_load_lds(
      (const __attribute__((address_space(1))) void*)g,
      (__attribute__((address_space(3))) void*)l,
      16, 0, 0);
}

// ---------------- fused convert + CAM GEMM + softmax + S-colsum ----------------
// Block: 512 threads (8 waves), one 64-row tile, full C=512 (softmax in-block).
//
// Replaces convert_pool + cam: F read ONCE (fp32), no Ft round-trip, and NO
// pooling here — logits use the identity pooled@W^T = (1/T) * sum_t CAM[t,:],
// so the epilogue just emits per-block column sums of S (Ssum[512]/block).
//
// A-path: per stage, each wave DMAs its OWN 1-KB fp32 segment of F into
// Fs[buf] (global_load_lds; zero registers held), then converts its own 16 B
// per lane (ds_read float4 -> 4x f2bf -> ds_write_b64) into frag-ordered
// As[buf]. Because convert reads only the segment the same wave DMA'd, the
// counted vmcnt wait publishes it intra-wave; the single end-of-phase barrier
// publishes As (bf16) for all waves. ONE barrier per stage.
//
// Counted vmcnt (uniform across waves): per phase each wave issues
// 1 A-DMA + 4 B-loads; at the wait, allowed outstanding = DMA(t+2)+B(t+1)x4
// -> s_waitcnt vmcnt(5) forces B(t) (this phase's operand) and DMA(t+1)
// (next phase's convert input) complete. vmcnt never drains to 0 in-loop.
//
// B-path (R5/R6, proven): frag-ordered Wt (1 MB, L2-resident), one coalesced
// 1-KB global_load_dwordx4 per (stage,ni) per wave, register double-buffered
// b0/b1 with static names (rule #20).
//
// R7 lesson applied: no fv registers held across phases, no pool butterfly in
// the critical section -> reg peak back to ~R6 level (no scratch spill).
__global__ __launch_bounds__(512, 4) void cam_all_kernel(
    const float* __restrict__ F,             // fp32 [32768,1024]
    const unsigned short* __restrict__ Wt,   // bf16 frag-ordered [32][512][4][8e]
    float* __restrict__ Ssum,                // [512][512] per-block S col-sums
    float* __restrict__ out_soft,
    float* __restrict__ out_raw)
{
  __shared__ alignas(16) float Fs[2][2048];            // 2 x 8 KB fp32 staging
  __shared__ alignas(16) unsigned short As[2][2048];   // 2 x 4 KB bf16 frags
  __shared__ float redmax[NWAVE][BM];                  // 2 KB
  __shared__ float redsum[NWAVE][BM];                  // 2 KB

  const int tid    = threadIdx.x;
  const int wave   = tid >> 6;
  const int lane   = tid & 63;
  const int lane15 = lane & 15;
  const int quad   = lane >> 4;
  const int l3     = lane >> 3;    // 0..7: row within wave's 8-row segment
  const int l7     = lane & 7;     // 0..7: float4 slot within 32-k row
  const int r64    = blockIdx.x;
  const int m0     = r64 * BM;
  const int chunk  = lane15 * 4 + quad;     // 0..63

  // A DMA source: row m0 + wave*8 + l3, k-offset s*32 + l7*4
  const float* fsrc = F + (size_t)(m0 + wave * 8 + l3) * ND + l7 * 4;
  // B per-lane base (elements): stage stride 16384, ni stride 512
  const unsigned short* wbase = Wt + wave * 2048 + chunk * 8;

  f32x4 acc[4][4];
  #pragma unroll
  for (int mi = 0; mi < 4; mi++)
    #pragma unroll
    for (int ni = 0; ni < 4; ni++)
      acc[mi][ni] = (f32x4){0.f, 0.f, 0.f, 0.f};

  auto stageF = [&](int s) {     // DMA wave's own 1-KB segment of stage s
    async_copy16(fsrc + s * BKS, &Fs[s & 1][wave * 256]);
  };
  auto loadB = [&](short8* dst, int s) {
    const unsigned short* p = wbase + s * 16384;
    #pragma unroll
    for (int ni = 0; ni < 4; ni++)
      dst[ni] = *reinterpret_cast<const short8*>(p + ni * 512);
  };
  auto convertA = [&](int s) {   // wave's own segment: Fs[s&1] -> As[s&1]
    const float4 v = *reinterpret_cast<const float4*>(
        &Fs[s & 1][wave * 256 + lane * 4]);
    ushort4 u;
    u.x = f2bf(v.x); u.y = f2bf(v.y); u.z = f2bf(v.z); u.w = f2bf(v.w);
    // frag-order elem for (row = wave*8+l3, kq = l7): row*32 + kq*4
    *reinterpret_cast<ushort4*>(
        &As[s & 1][wave * 256 + l3 * 32 + l7 * 4]) = u;
  };
  auto compute = [&](int buf, const short8* bf) {
    short8 af[4];
    #pragma unroll
    for (int mi = 0; mi < 4; mi++)
      af[mi] = *reinterpret_cast<const short8*>(&As[buf][mi * 512 + chunk * 8]);
    #pragma unroll
    for (int ni = 0; ni < 4; ni++)
      #pragma unroll
      for (int mi = 0; mi < 4; mi++)
        acc[mi][ni] = __builtin_amdgcn_mfma_f32_16x16x32_bf16(
            af[mi], bf[ni], acc[mi][ni], 0, 0, 0);
  };

  short8 b0[4], b1[4];

  // ---- prologue: DMA(0),DMA(1),B(0) in flight; convert(0); publish ----
  stageF(0);
  stageF(1);
  loadB(b0, 0);
  asm volatile("s_waitcnt vmcnt(5)" ::: "memory");   // DMA(0) done
  convertA(0);
  asm volatile("s_waitcnt lgkmcnt(0)" ::: "memory");
  __builtin_amdgcn_s_barrier();                      // As[0] published

  // ---- main loop: ONE barrier per stage; uniform vmcnt(5) ----
  #pragma unroll 1
  for (int t = 0; t < NSTAGE - 2; t += 2) {
    // even phase: tile t (As0, b0)
    stageF(t + 2);                                   // -> Fs[0]
    loadB(b1, t + 1);
    asm volatile("s_waitcnt vmcnt(5)" ::: "memory"); // B(t), DMA(t+1) done
    convertA(t + 1);                                 // Fs[1] -> As[1]
    __builtin_amdgcn_s_setprio(1);
    compute(0, b0);
    __builtin_amdgcn_s_setprio(0);
    asm volatile("s_waitcnt lgkmcnt(0)" ::: "memory");
    __builtin_amdgcn_s_barrier();                    // As[1] published

    // odd phase: tile t+1 (As1, b1)
    stageF(t + 3);                                   // -> Fs[1]
    loadB(b0, t + 2);
    asm volatile("s_waitcnt vmcnt(5)" ::: "memory"); // B(t+1), DMA(t+2) done
    convertA(t + 2);                                 // Fs[0] -> As[0]
    __builtin_amdgcn_s_setprio(1);
    compute(1, b1);
    __builtin_amdgcn_s_setprio(0);
    asm volatile("s_waitcnt lgkmcnt(0)" ::: "memory");
    __builtin_amdgcn_s_barrier();                    // As[0] published
  }

  // ---- tail: tiles 30,31 (no more staging) ----
  {
    loadB(b1, NSTAGE - 1);
    asm volatile("s_waitcnt vmcnt(4)" ::: "memory"); // B(30), DMA(31) done
    convertA(NSTAGE - 1);                            // Fs[1] -> As[1]
    __builtin_amdgcn_s_setprio(1);
    compute(0, b0);                                  // tile 30
    __builtin_amdgcn_s_setprio(0);
    asm volatile("s_waitcnt lgkmcnt(0)" ::: "memory");
    __builtin_amdgcn_s_barrier();                    // As[1] published

    asm volatile("s_waitcnt vmcnt(0)" ::: "memory"); // B(31) done
    __builtin_amdgcn_s_setprio(1);
    compute(1, b1);                                  // tile 31
    __builtin_amdgcn_s_setprio(0);
  }

  // ---- S column sums (replaces pooling; logits = (1/T)*sum_t S + bias) ----
  // lane's acc covers rows {quad*4+r + mi*16}: sum in-lane over mi,r (16 rows),
  // then shfl_xor 16,32 sums over the 4 quads -> all 64 rows of this block.
  #pragma unroll
  for (int ni = 0; ni < 4; ni++) {
    float s = 0.f;
    #pragma unroll
    for (int mi = 0; mi < 4; mi++)
      #pragma unroll
      for (int r = 0; r < 4; r++) s += acc[mi][ni][r];
    s += __shfl_xor(s, 16, 64);
    s += __shfl_xor(s, 32, 64);
    if (quad == 0)
      Ssum[(size_t)r64 * NC + wave * 64 + ni * 16 + lane15] = s;
  }

  // ---- epilogue: fused softmax over C=512 ----
  // C/D layout: col = lane15 (+wave*64+ni*16), row = quad*4 + reg (+mi*16)
  #pragma unroll
  for (int mi = 0; mi < 4; mi++)
    #pragma unroll
    for (int r = 0; r < 4; r++) {
      float m = acc[mi][0][r];
      #pragma unroll
      for (int ni = 1; ni < 4; ni++) m = fmaxf(m, acc[mi][ni][r]);
      #pragma unroll
      for (int off = 1; off < 16; off <<= 1) m = fmaxf(m, __shfl_xor(m, off, 64));
      if (lane15 == 0) redmax[wave][mi * 16 + quad * 4 + r] = m;
    }
  __syncthreads();

  float rsum[4][4];
  #pragma unroll
  for (int mi = 0; mi < 4; mi++)
    #pragma unroll
    for (int r = 0; r < 4; r++) {
      const int row = mi * 16 + quad * 4 + r;
      float m = redmax[0][row];
      #pragma unroll
      for (int w = 1; w < NWAVE; w++) m = fmaxf(m, redmax[w][row]);
      float s = 0.f;
      #pragma unroll
      for (int ni = 0; ni < 4; ni++) {
        const float e = __expf(acc[mi][ni][r] - m);
        acc[mi][ni][r] = e;
        s += e;
      }
      #pragma unroll
      for (int off = 1; off < 16; off <<= 1) s += __shfl_xor(s, off, 64);
      rsum[mi][r] = s;
    }
  if (lane15 == 0) {
    #pragma unroll
    for (int mi = 0; mi < 4; mi++)
      #pragma unroll
      for (int r = 0; r < 4; r++)
        redsum[wave][mi * 16 + quad * 4 + r] = rsum[mi][r];
  }
  __syncthreads();

  #pragma unroll
  for (int mi = 0; mi < 4; mi++)
    #pragma unroll
    for (int r = 0; r < 4; r++) {
      const int row = mi * 16 + quad * 4 + r;
      float s = redsum[0][row];
      #pragma unroll
      for (int w = 1; w < NWAVE; w++) s += redsum[w][row];
      const float inv = 1.f / s;
      const size_t gr = (size_t)(m0 + row) * NC;
      #pragma unroll
      for (int ni = 0; ni < 4; ni++) {
        const int col = wave * 64 + ni * 16 + lane15;
        const float v = acc[mi][ni][r] * inv;
        out_soft[gr + col] = v;
        out_raw [gr + col] = v;
      }
    }
}

// ---------------- W fp32 -> Wt bf16 fragment-ordered ----------------
// chunk g: q = g&3, c = (g>>2)&511, s = g>>11; Wt[g*8..+8] = bf16(W[c][s*32+q*8..+8])
__global__ __launch_bounds__(256) void convw_kernel(
    const float* __restrict__ W, unsigned short* __restrict__ Wt)
{
  const int g = blockIdx.x * 256 + threadIdx.x;   // 0..65535
  const int q = g & 3, c = (g >> 2) & 511, s = g >> 11;
  const float* src = W + (size_t)c * ND + s * 32 + q * 8;
  const float4 a = *reinterpret_cast<const float4*>(src);
  const float4 b = *reinterpret_cast<const float4*>(src + 4);
  ushort4 lo, hi;
  lo.x = f2bf(a.x); lo.y = f2bf(a.y); lo.z = f2bf(a.z); lo.w = f2bf(a.w);
  hi.x = f2bf(b.x); hi.y = f2bf(b.y); hi.z = f2bf(b.z); hi.w = f2bf(b.w);
  *reinterpret_cast<ushort4*>(Wt + (size_t)g * 8)     = lo;
  *reinterpret_cast<ushort4*>(Wt + (size_t)g * 8 + 4) = hi;
}

// ---------------- logits[b][c] = (1/T) * sum_z Ssum[b*32+z][c] + bias[c] ----------------
__global__ __launch_bounds__(512) void logits_kernel(
    const float* __restrict__ Ssum, const float* __restrict__ bias,
    float* __restrict__ out_logits)
{
  const int b = blockIdx.x;
  const int c = threadIdx.x;
  float s = 0.f;
  #pragma unroll
  for (int z = 0; z < 32; z++)
    s += Ssum[(size_t)(b * 32 + z) * NC + c];
  out_logits[b * NC + c] = s * (1.f / NT) + bias[c];
}

// ---------------- cross-entropy loss (fp32, wave-parallel) ----------------
__global__ __launch_bounds__(512) void loss_kernel(
    const float* __restrict__ logits, const int* __restrict__ labels,
    float* __restrict__ out_loss)
{
  __shared__ float term[16];
  const int tid  = threadIdx.x;
  const int wave = tid >> 6;
  const int lane = tid & 63;
  #pragma unroll
  for (int k = 0; k < 2; k++) {
    const int b = wave + k * 8;
    float v[8];
    float m = -3.4e38f;
    #pragma unroll
    for (int j = 0; j < 8; j++) {
      v[j] = logits[b * NC + j * 64 + lane];
      m = fmaxf(m, v[j]);
    }
    #pragma unroll
    for (int off = 1; off < 64; off <<= 1) m = fmaxf(m, __shfl_xor(m, off, 64));
    float e = 0.f;
    #pragma unroll
    for (int j = 0; j < 8; j++) e += expf(v[j] - m);
    #pragma unroll
    for (int off = 1; off < 64; off <<= 1) e += __shfl_xor(e, off, 64);
    if (lane == 0) {
      const int lab = labels[b];
      term[b] = -(logits[b * NC + lab] - m - logf(e));
    }
  }
  __syncthreads();
  if (tid == 0) {
    float a = 0.f;
    #pragma unroll
    for (int b = 0; b < 16; b++) a += term[b];
    out_loss[0] = a * (1.f / NB);
  }
}

extern "C" void kernel_launch(void* const* d_in, const int* in_sizes, int n_in,
                              void* d_out, int out_size, void* d_ws, size_t ws_size,
                              hipStream_t stream) {
  const float* F      = (const float*)d_in[0];   // [16,2048,1024]
  const int*   labels = (const int*)  d_in[1];   // [16]
  const float* W      = (const float*)d_in[2];   // [512,1024]
  const float* bias   = (const float*)d_in[3];   // [512]

  float* out        = (float*)d_out;
  float* out_soft   = out;
  float* out_raw    = out + (size_t)NM * NC;
  float* out_logits = out + (size_t)2 * NM * NC;
  float* out_loss   = out_logits + (size_t)NB * NC;

  // ws layout: Ssum [0, 1 MiB) | Wt [2 MiB, 3 MiB)
  char* ws = (char*)d_ws;
  float* Ssum = (float*)ws;                                     // 512*512 f32
  unsigned short* Wt = (unsigned short*)(ws + (2u << 20));      // 32*512*4*8 bf16

  convw_kernel<<<NC * ND / (256 * 8), 256, 0, stream>>>(W, Wt);
  cam_all_kernel<<<NM / BM, 512, 0, stream>>>(F, Wt, Ssum, out_soft, out_raw);
  logits_kernel<<<NB, 512, 0, stream>>>(Ssum, bias, out_logits);
  loss_kernel<<<1, 512, 0, stream>>>(out_logits, labels, out_loss);
}

// Round 9
// 281.706 us; speedup vs baseline: 1.1795x; 1.0103x over previous
//
#include <hip/hip_runtime.h>
#include <cstdint>

typedef __attribute__((ext_vector_type(8))) short short8;
typedef __attribute__((ext_vector_type(4))) float f32x4;

#define NB 16
#define NT 2048
#define ND 1024
#define NC 512
#define NM (NB*NT)   // 32768 rows

#define BM 64        // rows per block
#define BKS 32       // K per stage
#define NSTAGE (ND/BKS)  // 32
#define NWAVE 8      // 512 threads
#define AROW 40      // As row stride in elems (80 B: 16B-aligned, bank-uniform)

__device__ __forceinline__ unsigned short f2bf(float f){
  unsigned int u = __float_as_uint(f);
  u += 0x7fffu + ((u >> 16) & 1u);   // RNE; inputs are finite normals
  return (unsigned short)(u >> 16);
}

// async 16B global -> LDS DMA (per-lane global src; wave-uniform LDS base + lane*16)
__device__ __forceinline__ void async_copy16(const void* g, void* l) {
  __builtin_amdgcn_global_load_lds(
      (const __attribute__((address_space(1))) void*)g,
      (__attribute__((address_space(3))) void*)l,
      16, 0, 0);
}

// ---------------- fused convert + CAM GEMM + softmax + S-colsum ----------------
// R8 structure (proven: 111 us) with two changes:
//  (a) DMA lead deepened 1 -> 2 phases: Fs[4] ring, per-phase issue order
//      {loadB(t+1)x4, stageF(t+3)}; steady-state queue at the wait is
//      [DMA(t+1), B(t)x4, DMA(t+2), B(t+1)x4, DMA(t+3)] -> vmcnt(6) completes
//      exactly DMA(t+1)+B(t). HBM latency (~900cy) now covered by 2 phases;
//      B L2 latency by 1. Tail: vmcnt 6,5,4,0 (hand-derived, wave-uniform).
//  (b) As row stride 64B -> 80B: frag-read bank bases (row*20+quad*4)%32 are
//      uniform (8 grants/bank = structural min); fixes the 2.1M 8-way hot-bank
//      conflicts of the 64B layout. 80B is 16B-aligned so b128 reads survive.
// Everything else (B-path via frag-ordered Wt register loads, identity-pooling
// via S column sums, in-block softmax, single barrier/stage) unchanged.
__global__ __launch_bounds__(512, 4) void cam_all_kernel(
    const float* __restrict__ F,             // fp32 [32768,1024]
    const unsigned short* __restrict__ Wt,   // bf16 frag-ordered [32][512][4][8e]
    float* __restrict__ Ssum,                // [512][512] per-block S col-sums
    float* __restrict__ out_soft,
    float* __restrict__ out_raw)
{
  __shared__ alignas(16) float Fs[4][2048];            // 32 KB fp32 stage ring
  __shared__ alignas(16) unsigned short As[2][BM * AROW]; // 10 KB bf16 frags
  __shared__ float redmax[NWAVE][BM];                  // 2 KB
  __shared__ float redsum[NWAVE][BM];                  // 2 KB

  const int tid    = threadIdx.x;
  const int wave   = tid >> 6;
  const int lane   = tid & 63;
  const int lane15 = lane & 15;
  const int quad   = lane >> 4;
  const int l3     = lane >> 3;    // 0..7: row within wave's 8-row segment
  const int l7     = lane & 7;     // 0..7: float4 slot within 32-k row
  const int r64    = blockIdx.x;
  const int m0     = r64 * BM;
  const int chunk  = lane15 * 4 + quad;     // 0..63

  // A DMA source: row m0 + wave*8 + l3, k-offset s*32 + l7*4
  const float* fsrc = F + (size_t)(m0 + wave * 8 + l3) * ND + l7 * 4;
  // B per-lane base (elements): stage stride 16384, ni stride 512
  const unsigned short* wbase = Wt + wave * 2048 + chunk * 8;

  f32x4 acc[4][4];
  #pragma unroll
  for (int mi = 0; mi < 4; mi++)
    #pragma unroll
    for (int ni = 0; ni < 4; ni++)
      acc[mi][ni] = (f32x4){0.f, 0.f, 0.f, 0.f};

  auto stageF = [&](int s) {     // DMA wave's own 1-KB segment of stage s
    async_copy16(fsrc + s * BKS, &Fs[s & 3][wave * 256]);
  };
  auto loadB = [&](short8* dst, int s) {
    const unsigned short* p = wbase + s * 16384;
    #pragma unroll
    for (int ni = 0; ni < 4; ni++)
      dst[ni] = *reinterpret_cast<const short8*>(p + ni * 512);
  };
  auto convertA = [&](int s) {   // wave's own segment: Fs[s&3] -> As[s&1]
    const float4 v = *reinterpret_cast<const float4*>(
        &Fs[s & 3][wave * 256 + lane * 4]);
    ushort4 u;
    u.x = f2bf(v.x); u.y = f2bf(v.y); u.z = f2bf(v.z); u.w = f2bf(v.w);
    // (row = wave*8+l3, kq = l7) -> elem row*AROW + l7*4
    *reinterpret_cast<ushort4*>(
        &As[s & 1][(wave * 8 + l3) * AROW + l7 * 4]) = u;
  };
  auto compute = [&](int buf, const short8* bf) {
    short8 af[4];
    #pragma unroll
    for (int mi = 0; mi < 4; mi++)
      af[mi] = *reinterpret_cast<const short8*>(
          &As[buf][(mi * 16 + lane15) * AROW + quad * 8]);
    #pragma unroll
    for (int ni = 0; ni < 4; ni++)
      #pragma unroll
      for (int mi = 0; mi < 4; mi++)
        acc[mi][ni] = __builtin_amdgcn_mfma_f32_16x16x32_bf16(
            af[mi], bf[ni], acc[mi][ni], 0, 0, 0);
  };

  short8 b0[4], b1[4];

  // ---- prologue: queue shaped to the loop invariant ----
  stageF(0);                                         // Fs[0]
  stageF(1);                                         // Fs[1]
  loadB(b0, 0);
  stageF(2);                                         // Fs[2]
  asm volatile("s_waitcnt vmcnt(6)" ::: "memory");   // DMA(0) done; keep
                                                     // DMA(1),B(0)x4,DMA(2)
  convertA(0);                                       // -> As[0]
  asm volatile("s_waitcnt lgkmcnt(0)" ::: "memory");
  __builtin_amdgcn_s_barrier();                      // As[0] published

  // ---- main loop: tiles 0..27; one barrier/stage; vmcnt(6) steady ----
  #pragma unroll 1
  for (int t = 0; t < NSTAGE - 4; t += 2) {
    // even phase: tile t (As0, b0)
    loadB(b1, t + 1);
    stageF(t + 3);
    asm volatile("s_waitcnt vmcnt(6)" ::: "memory"); // B(t), DMA(t+1) done
    convertA(t + 1);                                 // -> As[1]
    __builtin_amdgcn_s_setprio(1);
    compute(0, b0);
    __builtin_amdgcn_s_setprio(0);
    asm volatile("s_waitcnt lgkmcnt(0)" ::: "memory");
    __builtin_amdgcn_s_barrier();                    // As[1] published

    // odd phase: tile t+1 (As1, b1)
    loadB(b0, t + 2);
    stageF(t + 4);
    asm volatile("s_waitcnt vmcnt(6)" ::: "memory"); // B(t+1), DMA(t+2) done
    convertA(t + 2);                                 // -> As[0]
    __builtin_amdgcn_s_setprio(1);
    compute(1, b1);
    __builtin_amdgcn_s_setprio(0);
    asm volatile("s_waitcnt lgkmcnt(0)" ::: "memory");
    __builtin_amdgcn_s_barrier();                    // As[0] published
  }

  // ---- tail: tiles 28..31 (staging winds down; counts hand-derived) ----
  {
    // tile 28 (As0,b0): last stageF (DMA(31))
    loadB(b1, 29);
    stageF(31);
    asm volatile("s_waitcnt vmcnt(6)" ::: "memory"); // B(28), DMA(29) done
    convertA(29);
    __builtin_amdgcn_s_setprio(1);
    compute(0, b0);
    __builtin_amdgcn_s_setprio(0);
    asm volatile("s_waitcnt lgkmcnt(0)" ::: "memory");
    __builtin_amdgcn_s_barrier();

    // tile 29 (As1,b1): queue [DMA(30),B(29)x4,DMA(31)] + B(30)x4
    loadB(b0, 30);
    asm volatile("s_waitcnt vmcnt(5)" ::: "memory"); // B(29), DMA(30) done
    convertA(30);
    __builtin_amdgcn_s_setprio(1);
    compute(1, b1);
    __builtin_amdgcn_s_setprio(0);
    asm volatile("s_waitcnt lgkmcnt(0)" ::: "memory");
    __builtin_amdgcn_s_barrier();

    // tile 30 (As0,b0): queue [DMA(31),B(30)x4] + B(31)x4
    loadB(b1, 31);
    asm volatile("s_waitcnt vmcnt(4)" ::: "memory"); // B(30), DMA(31) done
    convertA(31);
    __builtin_amdgcn_s_setprio(1);
    compute(0, b0);
    __builtin_amdgcn_s_setprio(0);
    asm volatile("s_waitcnt lgkmcnt(0)" ::: "memory");
    __builtin_amdgcn_s_barrier();

    // tile 31 (As1,b1)
    asm volatile("s_waitcnt vmcnt(0)" ::: "memory"); // B(31) done
    __builtin_amdgcn_s_setprio(1);
    compute(1, b1);
    __builtin_amdgcn_s_setprio(0);
  }

  // ---- S column sums (identity pooling; logits = (1/T)*sum_t S + bias) ----
  #pragma unroll
  for (int ni = 0; ni < 4; ni++) {
    float s = 0.f;
    #pragma unroll
    for (int mi = 0; mi < 4; mi++)
      #pragma unroll
      for (int r = 0; r < 4; r++) s += acc[mi][ni][r];
    s += __shfl_xor(s, 16, 64);
    s += __shfl_xor(s, 32, 64);
    if (quad == 0)
      Ssum[(size_t)r64 * NC + wave * 64 + ni * 16 + lane15] = s;
  }

  // ---- epilogue: fused softmax over C=512 ----
  // C/D layout: col = lane15 (+wave*64+ni*16), row = quad*4 + reg (+mi*16)
  #pragma unroll
  for (int mi = 0; mi < 4; mi++)
    #pragma unroll
    for (int r = 0; r < 4; r++) {
      float m = acc[mi][0][r];
      #pragma unroll
      for (int ni = 1; ni < 4; ni++) m = fmaxf(m, acc[mi][ni][r]);
      #pragma unroll
      for (int off = 1; off < 16; off <<= 1) m = fmaxf(m, __shfl_xor(m, off, 64));
      if (lane15 == 0) redmax[wave][mi * 16 + quad * 4 + r] = m;
    }
  __syncthreads();

  float rsum[4][4];
  #pragma unroll
  for (int mi = 0; mi < 4; mi++)
    #pragma unroll
    for (int r = 0; r < 4; r++) {
      const int row = mi * 16 + quad * 4 + r;
      float m = redmax[0][row];
      #pragma unroll
      for (int w = 1; w < NWAVE; w++) m = fmaxf(m, redmax[w][row]);
      float s = 0.f;
      #pragma unroll
      for (int ni = 0; ni < 4; ni++) {
        const float e = __expf(acc[mi][ni][r] - m);
        acc[mi][ni][r] = e;
        s += e;
      }
      #pragma unroll
      for (int off = 1; off < 16; off <<= 1) s += __shfl_xor(s, off, 64);
      rsum[mi][r] = s;
    }
  if (lane15 == 0) {
    #pragma unroll
    for (int mi = 0; mi < 4; mi++)
      #pragma unroll
      for (int r = 0; r < 4; r++)
        redsum[wave][mi * 16 + quad * 4 + r] = rsum[mi][r];
  }
  __syncthreads();

  #pragma unroll
  for (int mi = 0; mi < 4; mi++)
    #pragma unroll
    for (int r = 0; r < 4; r++) {
      const int row = mi * 16 + quad * 4 + r;
      float s = redsum[0][row];
      #pragma unroll
      for (int w = 1; w < NWAVE; w++) s += redsum[w][row];
      const float inv = 1.f / s;
      const size_t gr = (size_t)(m0 + row) * NC;
      #pragma unroll
      for (int ni = 0; ni < 4; ni++) {
        const int col = wave * 64 + ni * 16 + lane15;
        const float v = acc[mi][ni][r] * inv;
        out_soft[gr + col] = v;
        out_raw [gr + col] = v;
      }
    }
}

// ---------------- W fp32 -> Wt bf16 fragment-ordered ----------------
// chunk g: q = g&3, c = (g>>2)&511, s = g>>11; Wt[g*8..+8] = bf16(W[c][s*32+q*8..+8])
__global__ __launch_bounds__(256) void convw_kernel(
    const float* __restrict__ W, unsigned short* __restrict__ Wt)
{
  const int g = blockIdx.x * 256 + threadIdx.x;   // 0..65535
  const int q = g & 3, c = (g >> 2) & 511, s = g >> 11;
  const float* src = W + (size_t)c * ND + s * 32 + q * 8;
  const float4 a = *reinterpret_cast<const float4*>(src);
  const float4 b = *reinterpret_cast<const float4*>(src + 4);
  ushort4 lo, hi;
  lo.x = f2bf(a.x); lo.y = f2bf(a.y); lo.z = f2bf(a.z); lo.w = f2bf(a.w);
  hi.x = f2bf(b.x); hi.y = f2bf(b.y); hi.z = f2bf(b.z); hi.w = f2bf(b.w);
  *reinterpret_cast<ushort4*>(Wt + (size_t)g * 8)     = lo;
  *reinterpret_cast<ushort4*>(Wt + (size_t)g * 8 + 4) = hi;
}

// ---------------- logits[b][c] = (1/T) * sum_z Ssum[b*32+z][c] + bias[c] ----------------
__global__ __launch_bounds__(512) void logits_kernel(
    const float* __restrict__ Ssum, const float* __restrict__ bias,
    float* __restrict__ out_logits)
{
  const int b = blockIdx.x;
  const int c = threadIdx.x;
  float s = 0.f;
  #pragma unroll
  for (int z = 0; z < 32; z++)
    s += Ssum[(size_t)(b * 32 + z) * NC + c];
  out_logits[b * NC + c] = s * (1.f / NT) + bias[c];
}

// ---------------- cross-entropy loss (fp32, wave-parallel) ----------------
__global__ __launch_bounds__(512) void loss_kernel(
    const float* __restrict__ logits, const int* __restrict__ labels,
    float* __restrict__ out_loss)
{
  __shared__ float term[16];
  const int tid  = threadIdx.x;
  const int wave = tid >> 6;
  const int lane = tid & 63;
  #pragma unroll
  for (int k = 0; k < 2; k++) {
    const int b = wave + k * 8;
    float v[8];
    float m = -3.4e38f;
    #pragma unroll
    for (int j = 0; j < 8; j++) {
      v[j] = logits[b * NC + j * 64 + lane];
      m = fmaxf(m, v[j]);
    }
    #pragma unroll
    for (int off = 1; off < 64; off <<= 1) m = fmaxf(m, __shfl_xor(m, off, 64));
    float e = 0.f;
    #pragma unroll
    for (int j = 0; j < 8; j++) e += expf(v[j] - m);
    #pragma unroll
    for (int off = 1; off < 64; off <<= 1) e += __shfl_xor(e, off, 64);
    if (lane == 0) {
      const int lab = labels[b];
      term[b] = -(logits[b * NC + lab] - m - logf(e));
    }
  }
  __syncthreads();
  if (tid == 0) {
    float a = 0.f;
    #pragma unroll
    for (int b = 0; b < 16; b++) a += term[b];
    out_loss[0] = a * (1.f / NB);
  }
}

extern "C" void kernel_launch(void* const* d_in, const int* in_sizes, int n_in,
                              void* d_out, int out_size, void* d_ws, size_t ws_size,
                              hipStream_t stream) {
  const float* F      = (const float*)d_in[0];   // [16,2048,1024]
  const int*   labels = (const int*)  d_in[1];   // [16]
  const float* W      = (const float*)d_in[2];   // [512,1024]
  const float* bias   = (const float*)d_in[3];   // [512]

  float* out        = (float*)d_out;
  float* out_soft   = out;
  float* out_raw    = out + (size_t)NM * NC;
  float* out_logits = out + (size_t)2 * NM * NC;
  float* out_loss   = out_logits + (size_t)NB * NC;

  // ws layout: Ssum [0, 1 MiB) | Wt [2 MiB, 3 MiB)
  char* ws = (char*)d_ws;
  float* Ssum = (float*)ws;                                     // 512*512 f32
  unsigned short* Wt = (unsigned short*)(ws + (2u << 20));      // 32*512*4*8 bf16

  convw_kernel<<<NC * ND / (256 * 8), 256, 0, stream>>>(W, Wt);
  cam_all_kernel<<<NM / BM, 512, 0, stream>>>(F, Wt, Ssum, out_soft, out_raw);
  logits_kernel<<<NB, 512, 0, stream>>>(Ssum, bias, out_logits);
  loss_kernel<<<1, 512, 0, stream>>>(out_logits, labels, out_loss);
}

// Round 10
// 276.997 us; speedup vs baseline: 1.1996x; 1.0170x over previous
//
#include <hip/hip_runtime.h>
#include <cstdint>

typedef __attribute__((ext_vector_type(8))) short short8;
typedef __attribute__((ext_vector_type(4))) float f32x4;

#define NB 16
#define NT 2048
#define ND 1024
#define NC 512
#define NM (NB*NT)   // 32768 rows

#define BM 128       // rows per block (1 block/CU: 256 blocks)
#define NBLK (NM/BM) // 256
#define BKS 32       // K per stage
#define NSTAGE (ND/BKS)  // 32
#define NWAVE 8      // 512 threads
#define AROW 40      // As row stride in elems (80 B: 16B-aligned, bank-uniform)

__device__ __forceinline__ unsigned short f2bf(float f){
  unsigned int u = __float_as_uint(f);
  u += 0x7fffu + ((u >> 16) & 1u);   // RNE; inputs are finite normals
  return (unsigned short)(u >> 16);
}

// async 16B global -> LDS DMA (per-lane global src; wave-uniform LDS base + lane*16)
__device__ __forceinline__ void async_copy16(const void* g, void* l) {
  __builtin_amdgcn_global_load_lds(
      (const __attribute__((address_space(1))) void*)g,
      (__attribute__((address_space(3))) void*)l,
      16, 0, 0);
}

// ---------------- fused convert + CAM GEMM + softmax + S-colsum ----------------
// BM=128 / 1 block/CU: halves per-CU barrier-convoy count (32 vs 64) and
// halves B L2 traffic per FLOP; per-stage MFMA:vmem goes 1:1 -> 3:1.
// acc[8][4] = 128 VGPR -> __launch_bounds__(512,2) (256-VGPR budget).
//
// Per wave per stage vmem: 4 B-loads (1KB each) + 2 A-DMAs (1KB each).
// Issue order per phase: loadB(t+1)x4, stageF(t+2)x2.
// Steady-state queue at the wait: [B(t)x4, D(t+1)x2, B(t+1)x4, D(t+2)x2]
// -> vmcnt(6) completes exactly B(t) (this phase's MFMA operand) and
// D(t+1) (this phase's convert input). Never drains to 0 mid-loop.
// Tail (tiles 28..31): vmcnt 6, 6, 4, 0 — hand-traced.
//
// Fs coherence is intra-wave (each wave DMAs and converts only its own
// segment) -> no barrier needed for Fs reuse; the single per-stage barrier
// publishes As (bf16 fragments) block-wide.
__global__ __launch_bounds__(512, 2) void cam_all_kernel(
    const float* __restrict__ F,             // fp32 [32768,1024]
    const unsigned short* __restrict__ Wt,   // bf16 frag-ordered [32][512][4][8e]
    float* __restrict__ Ssum,                // [256][512] per-block S col-sums
    float* __restrict__ out_soft,
    float* __restrict__ out_raw)
{
  __shared__ alignas(16) float Fs[2][4096];               // 32 KB fp32 staging
  __shared__ alignas(16) unsigned short As[2][BM * AROW]; // 20 KB bf16 frags
  __shared__ float redmax[NWAVE][BM];                     // 4 KB
  __shared__ float redsum[NWAVE][BM];                     // 4 KB

  const int tid    = threadIdx.x;
  const int wave   = tid >> 6;
  const int lane   = tid & 63;
  const int lane15 = lane & 15;
  const int quad   = lane >> 4;
  const int l3     = lane >> 3;    // 0..7: row within an 8-row DMA segment
  const int l7     = lane & 7;     // 0..7: float4 slot within 32-k row
  const int r128   = blockIdx.x;
  const int m0     = r128 * BM;
  const int chunk  = lane15 * 4 + quad;     // 0..63

  // A DMA sources: wave's rows [wave*16, wave*16+16), two 8-row segments
  const float* fsrc0 = F + (size_t)(m0 + wave * 16 + l3) * ND + l7 * 4;
  const float* fsrc1 = fsrc0 + (size_t)8 * ND;
  // B per-lane base (elements): stage stride 16384, ni stride 512
  const unsigned short* wbase = Wt + wave * 2048 + chunk * 8;

  f32x4 acc[8][4];
  #pragma unroll
  for (int mi = 0; mi < 8; mi++)
    #pragma unroll
    for (int ni = 0; ni < 4; ni++)
      acc[mi][ni] = (f32x4){0.f, 0.f, 0.f, 0.f};

  auto stageF = [&](int s) {     // DMA wave's own 2-KB segment of stage s
    async_copy16(fsrc0 + s * BKS, &Fs[s & 1][wave * 512]);
    async_copy16(fsrc1 + s * BKS, &Fs[s & 1][wave * 512 + 256]);
  };
  auto loadB = [&](short8* dst, int s) {
    const unsigned short* p = wbase + s * 16384;
    #pragma unroll
    for (int ni = 0; ni < 4; ni++)
      dst[ni] = *reinterpret_cast<const short8*>(p + ni * 512);
  };
  auto convertA = [&](int s) {   // wave's own segment: Fs[s&1] -> As[s&1]
    #pragma unroll
    for (int j = 0; j < 2; j++) {
      const float4 v = *reinterpret_cast<const float4*>(
          &Fs[s & 1][wave * 512 + j * 256 + lane * 4]);
      ushort4 u;
      u.x = f2bf(v.x); u.y = f2bf(v.y); u.z = f2bf(v.z); u.w = f2bf(v.w);
      *reinterpret_cast<ushort4*>(
          &As[s & 1][(wave * 16 + j * 8 + l3) * AROW + l7 * 4]) = u;
    }
  };
  auto compute = [&](int buf, const short8* bf) {
    short8 af[8];
    #pragma unroll
    for (int mi = 0; mi < 8; mi++)
      af[mi] = *reinterpret_cast<const short8*>(
          &As[buf][(mi * 16 + lane15) * AROW + quad * 8]);
    #pragma unroll
    for (int ni = 0; ni < 4; ni++)
      #pragma unroll
      for (int mi = 0; mi < 8; mi++)
        acc[mi][ni] = __builtin_amdgcn_mfma_f32_16x16x32_bf16(
            af[mi], bf[ni], acc[mi][ni], 0, 0, 0);
  };

  short8 b0[4], b1[4];

  // ---- prologue: queue [D0x2, D1x2, B0x4]; wait D0; publish tile 0 ----
  stageF(0);
  stageF(1);
  loadB(b0, 0);
  asm volatile("s_waitcnt vmcnt(6)" ::: "memory");   // D0 done
  convertA(0);
  asm volatile("s_waitcnt lgkmcnt(0)" ::: "memory");
  __builtin_amdgcn_s_barrier();                      // As[0] published

  // ---- main loop: tiles 0..27; one barrier/stage; vmcnt(6) steady ----
  #pragma unroll 1
  for (int t = 0; t < NSTAGE - 4; t += 2) {
    // even phase: tile t (As0, b0)
    loadB(b1, t + 1);
    stageF(t + 2);
    asm volatile("s_waitcnt vmcnt(6)" ::: "memory"); // B(t), D(t+1) done
    convertA(t + 1);                                 // -> As[1]
    __builtin_amdgcn_s_setprio(1);
    compute(0, b0);
    __builtin_amdgcn_s_setprio(0);
    asm volatile("s_waitcnt lgkmcnt(0)" ::: "memory");
    __builtin_amdgcn_s_barrier();                    // As[1] published

    // odd phase: tile t+1 (As1, b1)
    loadB(b0, t + 2);
    stageF(t + 3);
    asm volatile("s_waitcnt vmcnt(6)" ::: "memory"); // B(t+1), D(t+2) done
    convertA(t + 2);                                 // -> As[0]
    __builtin_amdgcn_s_setprio(1);
    compute(1, b1);
    __builtin_amdgcn_s_setprio(0);
    asm volatile("s_waitcnt lgkmcnt(0)" ::: "memory");
    __builtin_amdgcn_s_barrier();                    // As[0] published
  }

  // ---- tail: tiles 28..31 ----
  {
    // tile 28 (As0,b0): last-but-one stageF
    loadB(b1, 29);
    stageF(30);
    asm volatile("s_waitcnt vmcnt(6)" ::: "memory"); // B28, D29 done
    convertA(29);
    __builtin_amdgcn_s_setprio(1);
    compute(0, b0);
    __builtin_amdgcn_s_setprio(0);
    asm volatile("s_waitcnt lgkmcnt(0)" ::: "memory");
    __builtin_amdgcn_s_barrier();

    // tile 29 (As1,b1): last stageF
    loadB(b0, 30);
    stageF(31);
    asm volatile("s_waitcnt vmcnt(6)" ::: "memory"); // B29, D30 done
    convertA(30);
    __builtin_amdgcn_s_setprio(1);
    compute(1, b1);
    __builtin_amdgcn_s_setprio(0);
    asm volatile("s_waitcnt lgkmcnt(0)" ::: "memory");
    __builtin_amdgcn_s_barrier();

    // tile 30 (As0,b0): queue [B30x4, D31x2] + B31x4 -> vmcnt(4)
    loadB(b1, 31);
    asm volatile("s_waitcnt vmcnt(4)" ::: "memory"); // B30, D31 done
    convertA(31);
    __builtin_amdgcn_s_setprio(1);
    compute(0, b0);
    __builtin_amdgcn_s_setprio(0);
    asm volatile("s_waitcnt lgkmcnt(0)" ::: "memory");
    __builtin_amdgcn_s_barrier();

    // tile 31 (As1,b1)
    asm volatile("s_waitcnt vmcnt(0)" ::: "memory"); // B31 done
    __builtin_amdgcn_s_setprio(1);
    compute(1, b1);
    __builtin_amdgcn_s_setprio(0);
  }

  // ---- S column sums (identity pooling; logits = (1/T)*sum_t S + bias) ----
  #pragma unroll
  for (int ni = 0; ni < 4; ni++) {
    float s = 0.f;
    #pragma unroll
    for (int mi = 0; mi < 8; mi++)
      #pragma unroll
      for (int r = 0; r < 4; r++) s += acc[mi][ni][r];
    s += __shfl_xor(s, 16, 64);
    s += __shfl_xor(s, 32, 64);
    if (quad == 0)
      Ssum[(size_t)r128 * NC + wave * 64 + ni * 16 + lane15] = s;
  }

  // ---- epilogue: fused softmax over C=512 ----
  // C/D layout: col = lane15 (+wave*64+ni*16), row = quad*4 + reg (+mi*16)
  #pragma unroll
  for (int mi = 0; mi < 8; mi++)
    #pragma unroll
    for (int r = 0; r < 4; r++) {
      float m = acc[mi][0][r];
      #pragma unroll
      for (int ni = 1; ni < 4; ni++) m = fmaxf(m, acc[mi][ni][r]);
      #pragma unroll
      for (int off = 1; off < 16; off <<= 1) m = fmaxf(m, __shfl_xor(m, off, 64));
      if (lane15 == 0) redmax[wave][mi * 16 + quad * 4 + r] = m;
    }
  __syncthreads();

  float rsum[8][4];
  #pragma unroll
  for (int mi = 0; mi < 8; mi++)
    #pragma unroll
    for (int r = 0; r < 4; r++) {
      const int row = mi * 16 + quad * 4 + r;
      float m = redmax[0][row];
      #pragma unroll
      for (int w = 1; w < NWAVE; w++) m = fmaxf(m, redmax[w][row]);
      float s = 0.f;
      #pragma unroll
      for (int ni = 0; ni < 4; ni++) {
        const float e = __expf(acc[mi][ni][r] - m);
        acc[mi][ni][r] = e;
        s += e;
      }
      #pragma unroll
      for (int off = 1; off < 16; off <<= 1) s += __shfl_xor(s, off, 64);
      rsum[mi][r] = s;
    }
  if (lane15 == 0) {
    #pragma unroll
    for (int mi = 0; mi < 8; mi++)
      #pragma unroll
      for (int r = 0; r < 4; r++)
        redsum[wave][mi * 16 + quad * 4 + r] = rsum[mi][r];
  }
  __syncthreads();

  #pragma unroll
  for (int mi = 0; mi < 8; mi++)
    #pragma unroll
    for (int r = 0; r < 4; r++) {
      const int row = mi * 16 + quad * 4 + r;
      float s = redsum[0][row];
      #pragma unroll
      for (int w = 1; w < NWAVE; w++) s += redsum[w][row];
      const float inv = 1.f / s;
      const size_t gr = (size_t)(m0 + row) * NC;
      #pragma unroll
      for (int ni = 0; ni < 4; ni++) {
        const int col = wave * 64 + ni * 16 + lane15;
        const float v = acc[mi][ni][r] * inv;
        out_soft[gr + col] = v;
        out_raw [gr + col] = v;
      }
    }
}

// ---------------- W fp32 -> Wt bf16 fragment-ordered ----------------
// chunk g: q = g&3, c = (g>>2)&511, s = g>>11; Wt[g*8..+8] = bf16(W[c][s*32+q*8..+8])
__global__ __launch_bounds__(256) void convw_kernel(
    const float* __restrict__ W, unsigned short* __restrict__ Wt)
{
  const int g = blockIdx.x * 256 + threadIdx.x;   // 0..65535
  const int q = g & 3, c = (g >> 2) & 511, s = g >> 11;
  const float* src = W + (size_t)c * ND + s * 32 + q * 8;
  const float4 a = *reinterpret_cast<const float4*>(src);
  const float4 b = *reinterpret_cast<const float4*>(src + 4);
  ushort4 lo, hi;
  lo.x = f2bf(a.x); lo.y = f2bf(a.y); lo.z = f2bf(a.z); lo.w = f2bf(a.w);
  hi.x = f2bf(b.x); hi.y = f2bf(b.y); hi.z = f2bf(b.z); hi.w = f2bf(b.w);
  *reinterpret_cast<ushort4*>(Wt + (size_t)g * 8)     = lo;
  *reinterpret_cast<ushort4*>(Wt + (size_t)g * 8 + 4) = hi;
}

// ---------------- logits[b][c] = (1/T) * sum_z Ssum[b*16+z][c] + bias[c] ----------------
__global__ __launch_bounds__(512) void logits_kernel(
    const float* __restrict__ Ssum, const float* __restrict__ bias,
    float* __restrict__ out_logits)
{
  const int b = blockIdx.x;
  const int c = threadIdx.x;
  float s = 0.f;
  #pragma unroll
  for (int z = 0; z < 16; z++)
    s += Ssum[(size_t)(b * 16 + z) * NC + c];
  out_logits[b * NC + c] = s * (1.f / NT) + bias[c];
}

// ---------------- cross-entropy loss (fp32, wave-parallel) ----------------
__global__ __launch_bounds__(512) void loss_kernel(
    const float* __restrict__ logits, const int* __restrict__ labels,
    float* __restrict__ out_loss)
{
  __shared__ float term[16];
  const int tid  = threadIdx.x;
  const int wave = tid >> 6;
  const int lane = tid & 63;
  #pragma unroll
  for (int k = 0; k < 2; k++) {
    const int b = wave + k * 8;
    float v[8];
    float m = -3.4e38f;
    #pragma unroll
    for (int j = 0; j < 8; j++) {
      v[j] = logits[b * NC + j * 64 + lane];
      m = fmaxf(m, v[j]);
    }
    #pragma unroll
    for (int off = 1; off < 64; off <<= 1) m = fmaxf(m, __shfl_xor(m, off, 64));
    float e = 0.f;
    #pragma unroll
    for (int j = 0; j < 8; j++) e += expf(v[j] - m);
    #pragma unroll
    for (int off = 1; off < 64; off <<= 1) e += __shfl_xor(e, off, 64);
    if (lane == 0) {
      const int lab = labels[b];
      term[b] = -(logits[b * NC + lab] - m - logf(e));
    }
  }
  __syncthreads();
  if (tid == 0) {
    float a = 0.f;
    #pragma unroll
    for (int b = 0; b < 16; b++) a += term[b];
    out_loss[0] = a * (1.f / NB);
  }
}

extern "C" void kernel_launch(void* const* d_in, const int* in_sizes, int n_in,
                              void* d_out, int out_size, void* d_ws, size_t ws_size,
                              hipStream_t stream) {
  const float* F      = (const float*)d_in[0];   // [16,2048,1024]
  const int*   labels = (const int*)  d_in[1];   // [16]
  const float* W      = (const float*)d_in[2];   // [512,1024]
  const float* bias   = (const float*)d_in[3];   // [512]

  float* out        = (float*)d_out;
  float* out_soft   = out;
  float* out_raw    = out + (size_t)NM * NC;
  float* out_logits = out + (size_t)2 * NM * NC;
  float* out_loss   = out_logits + (size_t)NB * NC;

  // ws layout: Ssum [0, 0.5 MiB) | Wt [2 MiB, 3 MiB)
  char* ws = (char*)d_ws;
  float* Ssum = (float*)ws;                                     // 256*512 f32
  unsigned short* Wt = (unsigned short*)(ws + (2u << 20));      // 32*512*4*8 bf16

  convw_kernel<<<NC * ND / (256 * 8), 256, 0, stream>>>(W, Wt);
  cam_all_kernel<<<NBLK, 512, 0, stream>>>(F, Wt, Ssum, out_soft, out_raw);
  logits_kernel<<<NB, 512, 0, stream>>>(Ssum, bias, out_logits);
  loss_kernel<<<1, 512, 0, stream>>>(out_logits, labels, out_loss);
}